// Round 1
// baseline (222.252 us; speedup 1.0000x reference)
//
#include <hip/hip_runtime.h>

#define N_NODES   10000
#define C_DIM     128
#define H_DIM     8
#define GRID      1024
#define BLOCK     256
#define NTHREADS  (GRID * BLOCK)
#define YZ_TOTAL  (N_NODES * H_DIM)
#define YZ_BLOCKS ((YZ_TOTAL + BLOCK - 1) / BLOCK)   /* 313 */
#define SPIN_LIMIT 200000

// Barrier state in device globals: zero-initialized at module load, NOT
// touched by the harness's workspace re-poisoning. Reset by last block out.
__device__ int g_yz_done  = 0;
__device__ int g_exit_ctr = 0;

__device__ __forceinline__ float sigmoid_fast(float v) {
    return __builtin_amdgcn_rcpf(1.f + __expf(-v));
}

// Emergency fallback (only if the barrier ever times out — preserves
// correctness under pathological scheduling; never taken in practice).
__device__ __noinline__ void direct_logits(const float* __restrict__ x,
                                           const float* __restrict__ W,
                                           const float* __restrict__ b,
                                           int r, int c, float* __restrict__ v) {
    float acc[H_DIM];
#pragma unroll
    for (int h = 0; h < H_DIM; ++h) acc[h] = b[h];
    const float* xr = x + (size_t)r * C_DIM;
    const float* xc = x + (size_t)c * C_DIM;
    for (int k = 0; k < C_DIM; ++k) {
        float va = xr[k], vb = xc[k];
#pragma unroll
        for (int h = 0; h < H_DIM; ++h) {
            acc[h] = fmaf(va, W[k * H_DIM + h], acc[h]);
            acc[h] = fmaf(vb, W[(C_DIM + k) * H_DIM + h], acc[h]);
        }
    }
#pragma unroll
    for (int h = 0; h < H_DIM; ++h) v[h] = acc[h];
}

__device__ __forceinline__ void edge_emit(float* __restrict__ out,
                                          const float* __restrict__ yz,
                                          int e, int r, int c, float a,
                                          const float* __restrict__ x,
                                          const float* __restrict__ W,
                                          const float* __restrict__ b,
                                          bool timeout) {
    float v[H_DIM];
    if (!timeout) {
        const float4* yp = (const float4*)(yz + (size_t)r * H_DIM);
        const float4* zp = (const float4*)(yz + YZ_TOTAL + (size_t)c * H_DIM);
        float4 y0 = yp[0], y1 = yp[1], z0 = zp[0], z1 = zp[1];
        v[0] = y0.x + z0.x; v[1] = y0.y + z0.y; v[2] = y0.z + z0.z; v[3] = y0.w + z0.w;
        v[4] = y1.x + z1.x; v[5] = y1.y + z1.y; v[6] = y1.z + z1.z; v[7] = y1.w + z1.w;
    } else {
        direct_logits(x, W, b, r, c, v);
    }
    const bool self = (r == c);
    float res[H_DIM];
#pragma unroll
    for (int h = 0; h < H_DIM; ++h) {
        float s = sigmoid_fast(v[h]);
        res[h] = self ? 1.f : s * a;
    }
    float4* op = (float4*)(out + (size_t)e * H_DIM);
    op[0] = make_float4(res[0], res[1], res[2], res[3]);
    op[1] = make_float4(res[4], res[5], res[6], res[7]);
}

extern "C" __global__ void __launch_bounds__(BLOCK, 4)
fused_attn(const float* __restrict__ x,  const int* __restrict__ ei,
           const float* __restrict__ ea, const float* __restrict__ W,
           const float* __restrict__ b,  float* __restrict__ out,
           float* __restrict__ yz, int E) {
    const int tid  = threadIdx.x;
    const int bid  = blockIdx.x;
    const int gtid = bid * BLOCK + tid;

    // ---------- Phase A: blocks 0..312 compute y/z tables ----------
    if (bid < YZ_BLOCKS) {
        if (gtid < YZ_TOTAL) {
            const int n = gtid >> 3;
            const int h = gtid & 7;
            const float4* xr4 = (const float4*)(x + (size_t)n * C_DIM);
            const float* wr = W + h;                      // Wr column h (L1-resident)
            const float* wc = W + C_DIM * H_DIM + h;      // Wc column h
            float accr = 0.f, accc = 0.f;
#pragma unroll 8
            for (int kk = 0; kk < C_DIM / 4; ++kk) {
                float4 xv = xr4[kk];                      // 16B/thread, deep MLP
                const int kb = kk * 4 * H_DIM;
                accr = fmaf(xv.x, wr[kb],      accr);
                accr = fmaf(xv.y, wr[kb + 8],  accr);
                accr = fmaf(xv.z, wr[kb + 16], accr);
                accr = fmaf(xv.w, wr[kb + 24], accr);
                accc = fmaf(xv.x, wc[kb],      accc);
                accc = fmaf(xv.y, wc[kb + 8],  accc);
                accc = fmaf(xv.z, wc[kb + 16], accc);
                accc = fmaf(xv.w, wc[kb + 24], accc);
            }
            yz[gtid]            = accr + b[h];
            yz[YZ_TOTAL + gtid] = accc;
        }
        __syncthreads();
        if (tid == 0) {
            __threadfence();  // release: write back yz (cross-XCD visibility)
            __hip_atomic_fetch_add(&g_yz_done, 1, __ATOMIC_RELEASE,
                                   __HIP_MEMORY_SCOPE_AGENT);
        }
    }

    // ---------- Phase B (all blocks, overlaps Phase A): yz-independent work ----------
    const int e0 = gtid, e1 = gtid + NTHREADS, e2 = gtid + 2 * NTHREADS;
    const bool h0 = e0 < E, h1 = e1 < E, h2 = e2 < E;
    int   r0 = 0, c0 = 0, r1 = 0, c1 = 0, r2 = 0, c2 = 0;
    float a0 = 0.f, a1 = 0.f, a2 = 0.f;
    const size_t ib = (size_t)E * H_DIM;
    if (h0) { r0 = ei[e0]; c0 = ei[E + e0]; a0 = ea[e0]; }
    if (h1) { r1 = ei[e1]; c1 = ei[E + e1]; a1 = ea[e1]; }
    if (h2) { r2 = ei[e2]; c2 = ei[E + e2]; a2 = ea[e2]; }
    if (h0) { out[ib + e0] = (float)r0; out[ib + E + e0] = (float)c0; }
    if (h1) { out[ib + e1] = (float)r1; out[ib + E + e1] = (float)c1; }
    if (h2) { out[ib + e2] = (float)r2; out[ib + E + e2] = (float)c2; }

    // ---------- Device-wide barrier: wait for all yz producers ----------
    __shared__ int s_to;
    if (tid == 0) {
        int spins = 0, to = 0;
        while (__hip_atomic_load(&g_yz_done, __ATOMIC_ACQUIRE,
                                 __HIP_MEMORY_SCOPE_AGENT) < YZ_BLOCKS) {
            __builtin_amdgcn_s_sleep(2);
            if (++spins > SPIN_LIMIT) { to = 1; break; }
        }
        s_to = to;
    }
    __syncthreads();
    __threadfence();  // acquire: drop any stale yz lines in this CU/XCD
    const bool timeout = (s_to != 0);

    // ---------- Phase C: gather + sigmoid + store ----------
    if (h0) edge_emit(out, yz, e0, r0, c0, a0, x, W, b, timeout);
    if (h1) edge_emit(out, yz, e1, r1, c1, a1, x, W, b, timeout);
    if (h2) edge_emit(out, yz, e2, r2, c2, a2, x, W, b, timeout);
    // Generic tail (dead code for E = 640000; robustness for other E)
    for (int e = gtid + 3 * NTHREADS; e < E; e += NTHREADS) {
        int r = ei[e], c = ei[E + e]; float a = ea[e];
        out[ib + e] = (float)r; out[ib + E + e] = (float)c;
        edge_emit(out, yz, e, r, c, a, x, W, b, timeout);
    }

    // ---------- Reset barrier state for the next graph replay ----------
    __syncthreads();
    if (tid == 0) {
        int vv = __hip_atomic_fetch_add(&g_exit_ctr, 1, __ATOMIC_ACQ_REL,
                                        __HIP_MEMORY_SCOPE_AGENT);
        if (vv == GRID - 1) {
            __hip_atomic_store(&g_yz_done,  0, __ATOMIC_RELAXED, __HIP_MEMORY_SCOPE_AGENT);
            __hip_atomic_store(&g_exit_ctr, 0, __ATOMIC_RELAXED, __HIP_MEMORY_SCOPE_AGENT);
        }
    }
}

extern "C" void kernel_launch(void* const* d_in, const int* in_sizes, int n_in,
                              void* d_out, int out_size, void* d_ws, size_t ws_size,
                              hipStream_t stream) {
    const float* x  = (const float*)d_in[0];
    const int*   ei = (const int*)d_in[1];   // int32 on device per harness convention
    const float* ea = (const float*)d_in[2];
    const float* W  = (const float*)d_in[3];
    const float* b  = (const float*)d_in[4];
    float* out = (float*)d_out;
    float* yz  = (float*)d_ws;               // 2*N*H*4 = 640 KB
    const int E = in_sizes[2];               // 640000

    hipLaunchKernelGGL(fused_attn, dim3(GRID), dim3(BLOCK), 0, stream,
                       x, ei, ea, W, b, out, yz, E);
}

// Round 2
// 27.880 us; speedup vs baseline: 7.9718x; 7.9718x over previous
//
#include <hip/hip_runtime.h>

#define N_NODES   10000
#define C_DIM     128
#define H_DIM     8
#define BLOCK     256
#define YZ_TOTAL  (N_NODES * H_DIM)
#define YZ_BLOCKS ((YZ_TOTAL + BLOCK - 1) / BLOCK)   /* 313 */

// ---------------------------------------------------------------------------
// K1 (two roles, split by blockIdx):
//   blocks [0, YZ_BLOCKS):       yz[n][h] tables  (y = x@Wr + b, z = x@Wc)
//   blocks [YZ_BLOCKS, ...):     index pass-through  out[8E + i] = (float)ei[i]
// The convert-copy has no dependency on yz; it rides in K1's latency slack
// (yz phase is 313 blocks, ~1.2 waves/SIMD, BW nearly idle).
// ---------------------------------------------------------------------------
__global__ void __launch_bounds__(BLOCK)
k1_yz_and_index(const float* __restrict__ x,
                const float* __restrict__ W,
                const float* __restrict__ b,
                const int*   __restrict__ ei,
                float* __restrict__ out,
                float* __restrict__ yz, int E) {
    const int bid = blockIdx.x;

    if (bid < YZ_BLOCKS) {
        // ---- yz tables: 8 threads per node (one per h), float4 x loads ----
        const int idx = bid * BLOCK + threadIdx.x;
        if (idx < YZ_TOTAL) {
            const int n = idx >> 3;
            const int h = idx & 7;
            const float4* xr4 = (const float4*)(x + (size_t)n * C_DIM);
            const float* wr = W + h;                   // Wr column h (4KB, L1-resident)
            const float* wc = W + C_DIM * H_DIM + h;   // Wc column h
            float accr = 0.f, accc = 0.f;
#pragma unroll 8
            for (int kk = 0; kk < C_DIM / 4; ++kk) {
                float4 xv = xr4[kk];
                const int kb = kk * 4 * H_DIM;
                accr = fmaf(xv.x, wr[kb],      accr);
                accr = fmaf(xv.y, wr[kb + 8],  accr);
                accr = fmaf(xv.z, wr[kb + 16], accr);
                accr = fmaf(xv.w, wr[kb + 24], accr);
                accc = fmaf(xv.x, wc[kb],      accc);
                accc = fmaf(xv.y, wc[kb + 8],  accc);
                accc = fmaf(xv.z, wc[kb + 16], accc);
                accc = fmaf(xv.w, wc[kb + 24], accc);
            }
            yz[idx]            = accr + b[h];
            yz[YZ_TOTAL + idx] = accc;
        }
    } else {
        // ---- index pass-through: flat int->float convert-copy of 2E elems ----
        const size_t ib = (size_t)E * H_DIM;
        const int t = (bid - YZ_BLOCKS) * BLOCK + threadIdx.x;
        const int i = t * 4;
        const int total = 2 * E;
        if (i + 3 < total) {
            int4 v = *(const int4*)(ei + i);
            *(float4*)(out + ib + i) =
                make_float4((float)v.x, (float)v.y, (float)v.z, (float)v.w);
        } else {
            for (int j = i; j < total; ++j) out[ib + j] = (float)ei[j];
        }
    }
}

// ---------------------------------------------------------------------------
// K2: pure gather + sigmoid + alpha store. 2 edges per thread.
// ---------------------------------------------------------------------------
__global__ void __launch_bounds__(BLOCK)
k2_edge_alpha(const int* __restrict__ ei,
              const float* __restrict__ ea,
              const float* __restrict__ yz,
              float* __restrict__ out, int E) {
    const int t = blockIdx.x * blockDim.x + threadIdx.x;
    const int e = t * 2;
    if (e >= E) return;

    const bool two = (e + 1 < E);
    int r0 = ei[e],     r1 = two ? ei[e + 1]     : 0;
    int c0 = ei[E + e], c1 = two ? ei[E + e + 1] : 0;
    float a0 = ea[e],   a1 = two ? ea[e + 1]     : 0.f;

    const float* ybase = yz;
    const float* zbase = yz + YZ_TOTAL;

    const float4* yp0 = (const float4*)(ybase + (size_t)r0 * H_DIM);
    const float4* zp0 = (const float4*)(zbase + (size_t)c0 * H_DIM);
    const float4* yp1 = (const float4*)(ybase + (size_t)r1 * H_DIM);
    const float4* zp1 = (const float4*)(zbase + (size_t)c1 * H_DIM);

    float4 y00 = yp0[0], y01 = yp0[1], z00 = zp0[0], z01 = zp0[1];
    float4 y10 = yp1[0], y11 = yp1[1], z10 = zp1[0], z11 = zp1[1];

    float v0[8] = { y00.x + z00.x, y00.y + z00.y, y00.z + z00.z, y00.w + z00.w,
                    y01.x + z01.x, y01.y + z01.y, y01.z + z01.z, y01.w + z01.w };
    float v1[8] = { y10.x + z10.x, y10.y + z10.y, y10.z + z10.z, y10.w + z10.w,
                    y11.x + z11.x, y11.y + z11.y, y11.z + z11.z, y11.w + z11.w };

    const bool self0 = (r0 == c0);
    const bool self1 = (r1 == c1);
    float res0[8], res1[8];
#pragma unroll
    for (int h = 0; h < 8; ++h) {
        float s0 = 1.f / (1.f + __expf(-v0[h]));
        float s1 = 1.f / (1.f + __expf(-v1[h]));
        res0[h] = self0 ? 1.f : s0 * a0;
        res1[h] = self1 ? 1.f : s1 * a1;
    }

    float4* op0 = (float4*)(out + (size_t)e * H_DIM);
    op0[0] = make_float4(res0[0], res0[1], res0[2], res0[3]);
    op0[1] = make_float4(res0[4], res0[5], res0[6], res0[7]);
    if (two) {
        float4* op1 = (float4*)(out + (size_t)(e + 1) * H_DIM);
        op1[0] = make_float4(res1[0], res1[1], res1[2], res1[3]);
        op1[1] = make_float4(res1[4], res1[5], res1[6], res1[7]);
    }
}

extern "C" void kernel_launch(void* const* d_in, const int* in_sizes, int n_in,
                              void* d_out, int out_size, void* d_ws, size_t ws_size,
                              hipStream_t stream) {
    const float* x  = (const float*)d_in[0];
    const int*   ei = (const int*)d_in[1];   // int32 on device per harness convention
    const float* ea = (const float*)d_in[2];
    const float* W  = (const float*)d_in[3];
    const float* b  = (const float*)d_in[4];
    float* out = (float*)d_out;
    float* yz  = (float*)d_ws;               // 2*N*H*4 = 640 KB
    const int E = in_sizes[2];               // 640000

    {
        // yz blocks + convert-copy blocks (4 elems/thread over 2E elements)
        const int conv_threads = (2 * E + 3) / 4;
        const int conv_blocks  = (conv_threads + BLOCK - 1) / BLOCK;   // 1250
        const int grid = YZ_BLOCKS + conv_blocks;                      // 1563
        hipLaunchKernelGGL(k1_yz_and_index, dim3(grid), dim3(BLOCK), 0, stream,
                           x, W, b, ei, out, yz, E);
    }
    {
        const int threads = (E + 1) / 2;
        const int grid = (threads + BLOCK - 1) / BLOCK;                // 1250
        hipLaunchKernelGGL(k2_edge_alpha, dim3(grid), dim3(BLOCK), 0, stream,
                           ei, ea, yz, out, E);
    }
}